// Round 6
// baseline (299.002 us; speedup 1.0000x reference)
//
#include <hip/hip_runtime.h>

#define DEV __device__ __forceinline__

constexpr int Bc = 2, Tc = 128, Dc = 256, Lc = 8, Hc = 4, DH = 64, Fc = 2048;
constexpr float EPS = 1e-5f, SCALE = 0.125f;  // 1/sqrt(64)
constexpr int NROWS = Bc * Tc * Lc;           // 2048 candidate rows
constexpr int SLAB = NROWS * Dc;              // 524288 floats

// ---- workspace layout (float offsets) ----
constexpr int OFF_K     = 0;                        // B*T*D frame keys
constexpr int OFF_VWOH  = OFF_K + Bc * Tc * Dc;     // B*T*H*D per-head v@Wo partials
constexpr int OFF_QCLS  = OFF_VWOH + Bc * Tc * Hc * Dc;
constexpr int OFF_KCLS  = OFF_QCLS + Dc;
constexpr int OFF_VWOHC = OFF_KCLS + Dc;            // H*D
constexpr int OFF_X0    = OFF_VWOHC + Hc * Dc;      // B*T*L*D x0; k_encz overwrites as ENC
constexpr int OFF_ENC   = OFF_X0;
constexpr int OFF_UP    = OFF_X0 + SLAB;            // 2*SLAB FFN half partial sums
constexpr int OFF_Z     = OFF_UP + 2 * SLAB;        // B*T*L eoc logits
constexpr int OFF_LST   = OFF_Z + NROWS;            // B*T ints chosen lengths
// total ~1.9M floats ~= 7.6 MB

DEV int imin(int a, int b) { return a < b ? a : b; }

// block = 256 threads (4 waves). red must be shared float[4].
DEV float blockReduceSum(float v, float* red) {
#pragma unroll
  for (int off = 32; off; off >>= 1) v += __shfl_down(v, off, 64);
  const int lane = threadIdx.x & 63;
  const int w = threadIdx.x >> 6;
  __syncthreads();  // protect red from previous use
  if (lane == 0) red[w] = v;
  __syncthreads();
  return red[0] + red[1] + red[2] + red[3];
}

// ---- K1: one row per block. LN1 + k/v projections + per-head v@Wo; q for CLS row. ----
__global__ __launch_bounds__(256) void k_prep(
    const float* __restrict__ frames, const float* __restrict__ cls,
    const float* __restrict__ Wq, const float* __restrict__ bq,
    const float* __restrict__ Wk, const float* __restrict__ bk,
    const float* __restrict__ Wv, const float* __restrict__ bv,
    const float* __restrict__ Wo,
    const float* __restrict__ g1, const float* __restrict__ b1,
    float* __restrict__ ws) {
  __shared__ float hsm[Dc];
  __shared__ float vsm[Dc];
  __shared__ float red[4];
  const int d = threadIdx.x;
  const int r = blockIdx.x;  // 0..B*T-1 frames, B*T = cls

  const float x = (r < Bc * Tc) ? frames[r * Dc + d] : cls[d];
  const float s = blockReduceSum(x, red);
  const float m = s * (1.0f / Dc);
  const float c = x - m;
  const float var = blockReduceSum(c * c, red) * (1.0f / Dc);
  hsm[d] = c * (1.0f / sqrtf(var + EPS)) * g1[d] + b1[d];
  __syncthreads();

  float ka = bk[d], va = bv[d];
  for (int c2 = 0; c2 < Dc; ++c2) {
    const float h = hsm[c2];
    ka = fmaf(h, Wk[c2 * Dc + d], ka);
    va = fmaf(h, Wv[c2 * Dc + d], va);
  }
  if (r < Bc * Tc) ws[OFF_K + r * Dc + d] = ka;
  else             ws[OFF_KCLS + d] = ka;
  vsm[d] = va;
  __syncthreads();

#pragma unroll
  for (int hh = 0; hh < Hc; ++hh) {
    float acc = 0.f;
    for (int c2 = 0; c2 < DH; ++c2)
      acc = fmaf(vsm[hh * DH + c2], Wo[(hh * DH + c2) * Dc + d], acc);
    if (r < Bc * Tc) ws[OFF_VWOH + r * (Hc * Dc) + hh * Dc + d] = acc;
    else             ws[OFF_VWOHC + hh * Dc + d] = acc;
  }
  if (r == Bc * Tc) {
    float qa = bq[d];
    for (int c2 = 0; c2 < Dc; ++c2) qa = fmaf(hsm[c2], Wq[c2 * Dc + d], qa);
    ws[OFF_QCLS + d] = qa;
  }
}

// ---- K2: per (b,i,F-half): attn prologue (duplicated per half, deterministic)
// + FFN half. Grid 512 = 2 blocks/CU so barrier stalls of one block are hidden
// by the other. 256 threads, LDS ~42KB. Phase 1: thread owns 4 f-cols, float4
// weight loads, double-buffered prefetch. Phase 2: wave owns 256-k slice;
// 4-partial deterministic LDS reduce. U_half -> global UP slab.
__global__ __launch_bounds__(256, 2) void k_half(
    const float* __restrict__ cls, const float* __restrict__ bo,
    const float* __restrict__ g2, const float* __restrict__ b2,
    const float* __restrict__ W1, const float* __restrict__ b1f,
    const float* __restrict__ W2, float* __restrict__ ws) {
  const int wg = blockIdx.x >> 1;   // b*T + i
  const int half = blockIdx.x & 1;
  const int i = wg & (Tc - 1);
  const int tid = threadIdx.x;
  const int wv = tid >> 6, lane = tid & 63;
  const int lmax = imin(Tc - i, Lc);

  __shared__ float ts[8][1024];   // 32KB; aliased as redb[4][8][256] after phase 2
  __shared__ float h2s[8][256];   // 8KB
  __shared__ float sv[Hc][Lc + 1];
  __shared__ float aP[Lc][Hc][Lc + 1];
  __shared__ __align__(16) float redA[Lc][4];
  __shared__ __align__(16) float redB[Lc][4];

  // ---- scores: wave = head ----
  {
    const float qv = ws[OFF_QCLS + wv * DH + lane];
    for (int j = 0; j <= Lc; ++j) {
      float p = 0.f;
      if (j == 0) p = qv * ws[OFF_KCLS + wv * DH + lane];
      else if (j - 1 < lmax) p = qv * ws[OFF_K + (wg + j - 1) * Dc + wv * DH + lane];
#pragma unroll
      for (int off = 32; off; off >>= 1) p += __shfl_down(p, off, 64);
      if (lane == 0) sv[wv][j] = p * SCALE;
    }
  }
  __syncthreads();

  // ---- softmax per candidate length ----
  if (tid < Lc * Hc) {
    const int l = (tid >> 2) + 1, h4 = tid & 3;
    if (l <= lmax) {
      float mx = -1e30f;
      for (int j = 0; j <= l; ++j) mx = fmaxf(mx, sv[h4][j]);
      float den = 0.f;
      for (int j = 0; j <= l; ++j) den += expf(sv[h4][j] - mx);
      const float inv = 1.f / den;
      for (int j = 0; j <= l; ++j) aP[l - 1][h4][j] = expf(sv[h4][j] - mx) * inv;
    }
  }
  __syncthreads();

  // ---- x0 accumulation (d = tid) + batched LN ----
  const int d = tid;
  float x0v[Lc];
  {
    const float base = cls[d] + bo[d];
#pragma unroll
    for (int l = 0; l < Lc; ++l) x0v[l] = base;
    for (int j = 0; j <= lmax; ++j) {
      const float* vwp = (j == 0) ? (ws + OFF_VWOHC)
                                  : (ws + OFF_VWOH + (wg + j - 1) * (Hc * Dc));
      for (int h4 = 0; h4 < Hc; ++h4) {
        const float w = vwp[h4 * Dc + d];
        const int lstart = (j == 0) ? 1 : j;
        for (int l = lstart; l <= lmax; ++l) x0v[l - 1] = fmaf(aP[l - 1][h4][j], w, x0v[l - 1]);
      }
    }
  }
#pragma unroll
  for (int l = 0; l < Lc; ++l) {
    float p = x0v[l];
#pragma unroll
    for (int off = 32; off; off >>= 1) p += __shfl_down(p, off, 64);
    if (lane == 0) redA[l][wv] = p;
  }
  __syncthreads();
  float mean[Lc];
#pragma unroll
  for (int l = 0; l < Lc; ++l) {
    const float4 s4 = *(const float4*)redA[l];
    mean[l] = (s4.x + s4.y + s4.z + s4.w) * (1.f / Dc);
  }
#pragma unroll
  for (int l = 0; l < Lc; ++l) {
    const float cv = x0v[l] - mean[l];
    float p = cv * cv;
#pragma unroll
    for (int off = 32; off; off >>= 1) p += __shfl_down(p, off, 64);
    if (lane == 0) redB[l][wv] = p;
  }
  __syncthreads();

  {
    const float g2d = g2[d], b2d = b2[d];
    for (int l = 1; l <= lmax; ++l) {
      const float4 s4 = *(const float4*)redB[l - 1];
      const float var = (s4.x + s4.y + s4.z + s4.w) * (1.f / Dc);
      const float rstd = 1.f / sqrtf(var + EPS);
      h2s[l - 1][d] = (x0v[l - 1] - mean[l - 1]) * rstd * g2d + b2d;
      if (half == 0) ws[OFF_X0 + (wg * Lc + l - 1) * Dc + d] = x0v[l - 1];
    }
    for (int l = lmax + 1; l <= Lc; ++l) {
      h2s[l - 1][d] = 0.f;
      if (half == 0) ws[OFF_X0 + (wg * Lc + l - 1) * Dc + d] = 0.f;
    }
  }
  __syncthreads();

  // ---- phase 1: T = relu(h2 @ W1[:, half] + b1f); thread owns 4 f-cols ----
  const int fg = half * 1024 + tid * 4;
  float t[8][4];
  {
    const float4 bb = *(const float4*)&b1f[fg];
#pragma unroll
    for (int r = 0; r < 8; ++r) { t[r][0] = bb.x; t[r][1] = bb.y; t[r][2] = bb.z; t[r][3] = bb.w; }
  }
  {
    float4 cur[4];
#pragma unroll
    for (int k = 0; k < 4; ++k) cur[k] = *(const float4*)&W1[k * Fc + fg];
    for (int c = 0; c < Dc; c += 4) {
      float4 nxt[4];
      const int cn = (c + 4 < Dc) ? c + 4 : 0;  // dummy reload at end (unused)
#pragma unroll
      for (int k = 0; k < 4; ++k) nxt[k] = *(const float4*)&W1[(cn + k) * Fc + fg];
#pragma unroll
      for (int r = 0; r < 8; ++r) {
        const float4 h = *(const float4*)&h2s[r][c];
        const float hv[4] = {h.x, h.y, h.z, h.w};
#pragma unroll
        for (int k = 0; k < 4; ++k) {
          t[r][0] = fmaf(hv[k], cur[k].x, t[r][0]);
          t[r][1] = fmaf(hv[k], cur[k].y, t[r][1]);
          t[r][2] = fmaf(hv[k], cur[k].z, t[r][2]);
          t[r][3] = fmaf(hv[k], cur[k].w, t[r][3]);
        }
      }
#pragma unroll
      for (int k = 0; k < 4; ++k) cur[k] = nxt[k];
    }
  }
#pragma unroll
  for (int r = 0; r < 8; ++r) {
    float4 v;
    v.x = fmaxf(t[r][0], 0.f); v.y = fmaxf(t[r][1], 0.f);
    v.z = fmaxf(t[r][2], 0.f); v.w = fmaxf(t[r][3], 0.f);
    *(float4*)&ts[r][tid * 4] = v;
  }
  __syncthreads();

  // ---- phase 2: U_half partial = T @ W2[half]; wave owns k-slice of 256 ----
  const int d4 = lane * 4;
  const int kbase = half * 1024 + wv * 256;  // global W2 row base
  float u[8][4];
#pragma unroll
  for (int r = 0; r < 8; ++r) { u[r][0] = 0.f; u[r][1] = 0.f; u[r][2] = 0.f; u[r][3] = 0.f; }
  {
    float4 cur[4];
#pragma unroll
    for (int k = 0; k < 4; ++k) cur[k] = *(const float4*)&W2[(kbase + k) * Dc + d4];
    for (int kk = 0; kk < 256; kk += 4) {
      float4 nxt[4];
      const int kn = (kk + 4 < 256) ? kk + 4 : 0;  // dummy reload at end
#pragma unroll
      for (int k = 0; k < 4; ++k) nxt[k] = *(const float4*)&W2[(kbase + kn + k) * Dc + d4];
#pragma unroll
      for (int r = 0; r < 8; ++r) {
        const float4 h = *(const float4*)&ts[r][wv * 256 + kk];
        const float hv[4] = {h.x, h.y, h.z, h.w};
#pragma unroll
        for (int k = 0; k < 4; ++k) {
          u[r][0] = fmaf(hv[k], cur[k].x, u[r][0]);
          u[r][1] = fmaf(hv[k], cur[k].y, u[r][1]);
          u[r][2] = fmaf(hv[k], cur[k].z, u[r][2]);
          u[r][3] = fmaf(hv[k], cur[k].w, u[r][3]);
        }
      }
#pragma unroll
      for (int k = 0; k < 4; ++k) cur[k] = nxt[k];
    }
  }
  __syncthreads();  // all ts reads done before aliasing as redb

  // ---- deterministic reduce of 4 wave partials; write U_half ----
  float* redb = &ts[0][0];  // [4][8][256]
#pragma unroll
  for (int r = 0; r < 8; ++r) {
    float4 v; v.x = u[r][0]; v.y = u[r][1]; v.z = u[r][2]; v.w = u[r][3];
    *(float4*)&redb[(wv * 8 + r) * 256 + d4] = v;
  }
  __syncthreads();
  {
    float* up = ws + OFF_UP + half * SLAB;
#pragma unroll
    for (int r = 0; r < 8; ++r) {
      const float s = ((redb[(0 * 8 + r) * 256 + tid] + redb[(1 * 8 + r) * 256 + tid]) +
                       redb[(2 * 8 + r) * 256 + tid]) + redb[(3 * 8 + r) * 256 + tid];
      up[(wg * Lc + r) * Dc + tid] = s;
    }
  }
}

// ---- K3: enc = x0 + U0 + U1 + b2f (in place); z GEMV; fused lstar select ----
__global__ __launch_bounds__(256) void k_encz(
    const float* __restrict__ We1, const float* __restrict__ be1,
    const float* __restrict__ We2, const float* __restrict__ be2,
    const float* __restrict__ b2f, float* __restrict__ ws) {
  const int wg = blockIdx.x;  // b*T + i
  const int f = threadIdx.x;
  const int lane = f & 63, wv = f >> 6;
  __shared__ float encs[8][Dc];
  __shared__ __align__(16) float zred[8][4];
  __shared__ float zs[8];
  const float bb = b2f[f];
#pragma unroll
  for (int r = 0; r < 8; ++r) {
    const int row = wg * Lc + r;
    const float e = ws[OFF_X0 + row * Dc + f] +
                    ws[OFF_UP + row * Dc + f] +
                    ws[OFF_UP + SLAB + row * Dc + f] + bb;
    ws[OFF_ENC + row * Dc + f] = e;  // in place over X0
    encs[r][f] = e;
  }
  __syncthreads();

  float g[8];
  const float be1f = be1[f];
#pragma unroll
  for (int r = 0; r < 8; ++r) g[r] = be1f;
  for (int c = 0; c < Dc; ++c) {
    const float w = We1[c * Dc + f];
#pragma unroll
    for (int r = 0; r < 8; ++r) g[r] = fmaf(encs[r][c], w, g[r]);
  }
  const float w2 = We2[f];
#pragma unroll
  for (int r = 0; r < 8; ++r) {
    float p = fmaxf(g[r], 0.f) * w2;
#pragma unroll
    for (int off = 32; off; off >>= 1) p += __shfl_down(p, off, 64);
    if (lane == 0) zred[r][wv] = p;
  }
  __syncthreads();
  if (f < 8) {
    const float4 s4 = *(const float4*)zred[f];
    zs[f] = s4.x + s4.y + s4.z + s4.w + be2[0];
    ws[OFF_Z + wg * Lc + f] = zs[f];
  }
  __syncthreads();
  if (f == 0) {
    const int i = wg & (Tc - 1);
    const int lmax = imin(Tc - i, Lc);
    int ls = lmax;
    for (int l = 1; l <= lmax; ++l) {
      if (zs[l - 1] > 0.f) { ls = l; break; }
    }
    ((int*)(ws + OFF_LST))[wg] = ls;
  }
}

// ---- K4: sequential walk via wave shuffles + emit ----
__global__ __launch_bounds__(256) void k_emit(float* __restrict__ ws, float* __restrict__ out) {
  const int b = blockIdx.x;
  const int tid = threadIdx.x;
  __shared__ int lst[Tc];
  __shared__ int path[Tc];
  __shared__ int cnt_s;
  const int* lsrc = (const int*)(ws + OFF_LST);
  if (tid < Tc) lst[tid] = lsrc[b * Tc + tid];
  __syncthreads();
  if (tid < 64) {  // wave 0: walk via register shuffles
    const int a0 = lst[tid], a1 = lst[64 + tid];
    int cur = 0, s = 0;
    while (cur < Tc) {
      const int l = (cur < 64) ? __shfl(a0, cur, 64) : __shfl(a1, cur - 64, 64);
      if (tid == 0) path[s] = cur * Lc + l - 1;
      ++s;
      cur += l;
    }
    if (tid == 0) cnt_s = s;
  }
  __syncthreads();
  const int c = cnt_s;
  for (int s0 = 0; s0 < Tc; s0 += 8) {
    float v[8];
#pragma unroll
    for (int k = 0; k < 8; ++k) {
      const int s = s0 + k;
      v[k] = (s < c) ? ws[OFF_ENC + (b * Tc * Lc + path[s]) * Dc + tid] : 0.f;
    }
#pragma unroll
    for (int k = 0; k < 8; ++k) out[(b * Tc + s0 + k) * Dc + tid] = v[k];
  }
  if (tid == 0) out[Bc * Tc * Dc + b] = (float)c;
}

extern "C" void kernel_launch(void* const* d_in, const int* in_sizes, int n_in,
                              void* d_out, int out_size, void* d_ws, size_t ws_size,
                              hipStream_t stream) {
  const float* frames = (const float*)d_in[0];
  const float* cls    = (const float*)d_in[1];
  const float* Wq     = (const float*)d_in[2];
  const float* bq     = (const float*)d_in[3];
  const float* Wk     = (const float*)d_in[4];
  const float* bk     = (const float*)d_in[5];
  const float* Wv     = (const float*)d_in[6];
  const float* bv     = (const float*)d_in[7];
  const float* Wo     = (const float*)d_in[8];
  const float* bo     = (const float*)d_in[9];
  const float* g1     = (const float*)d_in[10];
  const float* b1     = (const float*)d_in[11];
  const float* g2     = (const float*)d_in[12];
  const float* b2     = (const float*)d_in[13];
  const float* W1     = (const float*)d_in[14];
  const float* b1f    = (const float*)d_in[15];
  const float* W2     = (const float*)d_in[16];
  const float* b2f    = (const float*)d_in[17];
  const float* We1    = (const float*)d_in[18];
  const float* be1    = (const float*)d_in[19];
  const float* We2    = (const float*)d_in[20];
  const float* be2    = (const float*)d_in[21];
  float* ws = (float*)d_ws;
  float* out = (float*)d_out;

  k_prep<<<Bc * Tc + 1, 256, 0, stream>>>(frames, cls, Wq, bq, Wk, bk, Wv, bv, Wo, g1, b1, ws);
  k_half<<<2 * Bc * Tc, 256, 0, stream>>>(cls, bo, g2, b2, W1, b1f, W2, ws);
  k_encz<<<Bc * Tc, 256, 0, stream>>>(We1, be1, We2, be2, b2f, ws);
  k_emit<<<Bc, 256, 0, stream>>>(ws, out);
}

// Round 7
// 231.226 us; speedup vs baseline: 1.2931x; 1.2931x over previous
//
#include <hip/hip_runtime.h>

#define DEV __device__ __forceinline__

constexpr int Bc = 2, Tc = 128, Dc = 256, Lc = 8, Hc = 4, DH = 64, Fc = 2048;
constexpr float EPS = 1e-5f, SCALE = 0.125f;  // 1/sqrt(64)
constexpr int NROWS = Bc * Tc * Lc;           // 2048 candidate rows
constexpr int SLAB = NROWS * Dc;              // 524288 floats

// ---- workspace layout (float offsets) ----
constexpr int OFF_K     = 0;                        // B*T*D frame keys
constexpr int OFF_VWOH  = OFF_K + Bc * Tc * Dc;     // B*T*H*D per-head v@Wo partials
constexpr int OFF_QCLS  = OFF_VWOH + Bc * Tc * Hc * Dc;
constexpr int OFF_KCLS  = OFF_QCLS + Dc;
constexpr int OFF_VWOHC = OFF_KCLS + Dc;            // H*D
constexpr int OFF_ENC   = OFF_VWOHC + Hc * Dc;      // B*T*L*D encoder CLS outputs
constexpr int OFF_Z     = OFF_ENC + SLAB;           // B*T*L eoc logits
// total ~0.86M floats ~= 3.4 MB

DEV int imin(int a, int b) { return a < b ? a : b; }

// block = 256 threads (4 waves). red must be shared float[4].
DEV float blockReduceSum(float v, float* red) {
#pragma unroll
  for (int off = 32; off; off >>= 1) v += __shfl_down(v, off, 64);
  const int lane = threadIdx.x & 63;
  const int w = threadIdx.x >> 6;
  __syncthreads();  // protect red from previous use
  if (lane == 0) red[w] = v;
  __syncthreads();
  return red[0] + red[1] + red[2] + red[3];
}

// ---- K1: one row per block. LN1 + k/v projections + per-head v@Wo; q for CLS row. ----
__global__ __launch_bounds__(256) void k_prep(
    const float* __restrict__ frames, const float* __restrict__ cls,
    const float* __restrict__ Wq, const float* __restrict__ bq,
    const float* __restrict__ Wk, const float* __restrict__ bk,
    const float* __restrict__ Wv, const float* __restrict__ bv,
    const float* __restrict__ Wo,
    const float* __restrict__ g1, const float* __restrict__ b1,
    float* __restrict__ ws) {
  __shared__ float hsm[Dc];
  __shared__ float vsm[Dc];
  __shared__ float red[4];
  const int d = threadIdx.x;
  const int r = blockIdx.x;  // 0..B*T-1 frames, B*T = cls

  const float x = (r < Bc * Tc) ? frames[r * Dc + d] : cls[d];
  const float s = blockReduceSum(x, red);
  const float m = s * (1.0f / Dc);
  const float c = x - m;
  const float var = blockReduceSum(c * c, red) * (1.0f / Dc);
  hsm[d] = c * (1.0f / sqrtf(var + EPS)) * g1[d] + b1[d];
  __syncthreads();

  float ka = bk[d], va = bv[d];
  for (int c2 = 0; c2 < Dc; ++c2) {
    const float h = hsm[c2];
    ka = fmaf(h, Wk[c2 * Dc + d], ka);
    va = fmaf(h, Wv[c2 * Dc + d], va);
  }
  if (r < Bc * Tc) ws[OFF_K + r * Dc + d] = ka;
  else             ws[OFF_KCLS + d] = ka;
  vsm[d] = va;
  __syncthreads();

#pragma unroll
  for (int hh = 0; hh < Hc; ++hh) {
    float acc = 0.f;
    for (int c2 = 0; c2 < DH; ++c2)
      acc = fmaf(vsm[hh * DH + c2], Wo[(hh * DH + c2) * Dc + d], acc);
    if (r < Bc * Tc) ws[OFF_VWOH + r * (Hc * Dc) + hh * Dc + d] = acc;
    else             ws[OFF_VWOHC + hh * Dc + d] = acc;
  }
  if (r == Bc * Tc) {
    float qa = bq[d];
    for (int c2 = 0; c2 < Dc; ++c2) qa = fmaf(hsm[c2], Wq[c2 * Dc + d], qa);
    ws[OFF_QCLS + d] = qa;
  }
}

// ---- K2: FULLY FUSED per (b,i): scores + softmax + x0 + ln2 (in LDS) + FFN + enc + z.
// 256 blocks x 512 threads. FFN does full F=2048 in ONE pass: thread owns 4
// f-cols (float4 W1 loads), ts[8][2048]=64KB, phase 1 has zero barriers.
// Phase 2: 8 waves x disjoint 256-k slices; 3 FFN barriers total; deterministic
// 8-partial reduce in LDS aliased over dead ts.
__global__ __launch_bounds__(512) void k_fused(
    const float* __restrict__ cls, const float* __restrict__ bo,
    const float* __restrict__ g2, const float* __restrict__ b2,
    const float* __restrict__ W1, const float* __restrict__ b1f,
    const float* __restrict__ W2, const float* __restrict__ b2f,
    const float* __restrict__ We1, const float* __restrict__ be1,
    const float* __restrict__ We2, const float* __restrict__ be2,
    float* __restrict__ ws) {
  const int wg = blockIdx.x;  // b*T + i
  const int i = wg & (Tc - 1);
  const int tid = threadIdx.x;
  const int wv = tid >> 6, lane = tid & 63;
  const int lmax = imin(Tc - i, Lc);

  __shared__ __align__(16) float ts[8][2048];   // 64KB; aliased as redb[8][8][256]
  __shared__ __align__(16) float h2s[8][256];   // 8KB
  __shared__ __align__(16) float x0s[8][256];   // 8KB
  __shared__ __align__(16) float encs[8][256];  // 8KB
  __shared__ float sv[Hc][Lc + 1];
  __shared__ float aP[Lc][Hc][Lc + 1];
  __shared__ __align__(16) float redA[Lc][4];
  __shared__ __align__(16) float redB[Lc][4];
  __shared__ float zred[8][4];

  // ---- scores: waves 0-3, wave = head ----
  if (tid < 256) {
    const int hh = tid >> 6;
    const float qv = ws[OFF_QCLS + hh * DH + lane];
    for (int j = 0; j <= Lc; ++j) {
      float p = 0.f;
      if (j == 0) p = qv * ws[OFF_KCLS + hh * DH + lane];
      else if (j - 1 < lmax) p = qv * ws[OFF_K + (wg + j - 1) * Dc + hh * DH + lane];
#pragma unroll
      for (int off = 32; off; off >>= 1) p += __shfl_down(p, off, 64);
      if (lane == 0) sv[hh][j] = p * SCALE;
    }
  }
  __syncthreads();

  // ---- softmax per candidate length ----
  if (tid < Lc * Hc) {
    const int l = (tid >> 2) + 1, h4 = tid & 3;
    if (l <= lmax) {
      float mx = -1e30f;
      for (int j = 0; j <= l; ++j) mx = fmaxf(mx, sv[h4][j]);
      float den = 0.f;
      for (int j = 0; j <= l; ++j) den += expf(sv[h4][j] - mx);
      const float inv = 1.f / den;
      for (int j = 0; j <= l; ++j) aP[l - 1][h4][j] = expf(sv[h4][j] - mx) * inv;
    }
  }
  __syncthreads();

  // ---- x0 accumulation + LN round 1 (threads 0-255, d = tid) ----
  float x0v[Lc];
  if (tid < 256) {
    const int d = tid;
    const float base = cls[d] + bo[d];
#pragma unroll
    for (int l = 0; l < Lc; ++l) x0v[l] = base;
    for (int j = 0; j <= lmax; ++j) {
      const float* vwp = (j == 0) ? (ws + OFF_VWOHC)
                                  : (ws + OFF_VWOH + (wg + j - 1) * (Hc * Dc));
      for (int h4 = 0; h4 < Hc; ++h4) {
        const float w = vwp[h4 * Dc + d];
        const int lstart = (j == 0) ? 1 : j;
        for (int l = lstart; l <= lmax; ++l) x0v[l - 1] = fmaf(aP[l - 1][h4][j], w, x0v[l - 1]);
      }
    }
#pragma unroll
    for (int l = 0; l < Lc; ++l) {
      float p = x0v[l];
#pragma unroll
      for (int off = 32; off; off >>= 1) p += __shfl_down(p, off, 64);
      if (lane == 0) redA[l][tid >> 6] = p;
    }
  }
  __syncthreads();

  float mean[Lc];
  if (tid < 256) {
#pragma unroll
    for (int l = 0; l < Lc; ++l) {
      const float4 s4 = *(const float4*)redA[l];
      mean[l] = (s4.x + s4.y + s4.z + s4.w) * (1.f / Dc);
    }
#pragma unroll
    for (int l = 0; l < Lc; ++l) {
      const float cv = x0v[l] - mean[l];
      float p = cv * cv;
#pragma unroll
      for (int off = 32; off; off >>= 1) p += __shfl_down(p, off, 64);
      if (lane == 0) redB[l][tid >> 6] = p;
    }
  }
  __syncthreads();

  if (tid < 256) {
    const int d = tid;
    const float g2d = g2[d], b2d = b2[d];
    for (int l = 1; l <= lmax; ++l) {
      const float4 s4 = *(const float4*)redB[l - 1];
      const float var = (s4.x + s4.y + s4.z + s4.w) * (1.f / Dc);
      const float rstd = 1.f / sqrtf(var + EPS);
      h2s[l - 1][d] = (x0v[l - 1] - mean[l - 1]) * rstd * g2d + b2d;
      x0s[l - 1][d] = x0v[l - 1];
    }
    for (int l = lmax + 1; l <= Lc; ++l) {
      h2s[l - 1][d] = 0.f;
      x0s[l - 1][d] = 0.f;
    }
  }
  __syncthreads();

  // ---- FFN phase 1: T = relu(h2 @ W1 + b1f), full F in one pass, no barriers ----
  const int fg = tid * 4;  // thread owns 4 f-cols of 2048
  float t[8][4];
  {
    const float4 bb = *(const float4*)&b1f[fg];
#pragma unroll
    for (int r = 0; r < 8; ++r) { t[r][0] = bb.x; t[r][1] = bb.y; t[r][2] = bb.z; t[r][3] = bb.w; }
  }
  for (int c = 0; c < Dc; c += 4) {
    float4 w1v[4];
#pragma unroll
    for (int k = 0; k < 4; ++k) w1v[k] = *(const float4*)&W1[(c + k) * Fc + fg];
#pragma unroll
    for (int r = 0; r < 8; ++r) {
      const float4 h = *(const float4*)&h2s[r][c];
      const float hv[4] = {h.x, h.y, h.z, h.w};
#pragma unroll
      for (int k = 0; k < 4; ++k) {
        t[r][0] = fmaf(hv[k], w1v[k].x, t[r][0]);
        t[r][1] = fmaf(hv[k], w1v[k].y, t[r][1]);
        t[r][2] = fmaf(hv[k], w1v[k].z, t[r][2]);
        t[r][3] = fmaf(hv[k], w1v[k].w, t[r][3]);
      }
    }
  }
#pragma unroll
  for (int r = 0; r < 8; ++r) {
    float4 v;
    v.x = fmaxf(t[r][0], 0.f); v.y = fmaxf(t[r][1], 0.f);
    v.z = fmaxf(t[r][2], 0.f); v.w = fmaxf(t[r][3], 0.f);
    *(float4*)&ts[r][fg] = v;
  }
  __syncthreads();

  // ---- FFN phase 2: u = T @ W2; wave wv owns k-slice [wv*256, wv*256+256) ----
  const int d4 = lane * 4;
  float u[8][4];
#pragma unroll
  for (int r = 0; r < 8; ++r) { u[r][0] = 0.f; u[r][1] = 0.f; u[r][2] = 0.f; u[r][3] = 0.f; }
  for (int kk = 0; kk < 256; kk += 4) {
    const int kg = wv * 256 + kk;
    float4 w2v[4];
#pragma unroll
    for (int k = 0; k < 4; ++k) w2v[k] = *(const float4*)&W2[(kg + k) * Dc + d4];
#pragma unroll
    for (int r = 0; r < 8; ++r) {
      const float4 h = *(const float4*)&ts[r][kg];
      const float hv[4] = {h.x, h.y, h.z, h.w};
#pragma unroll
      for (int k = 0; k < 4; ++k) {
        u[r][0] = fmaf(hv[k], w2v[k].x, u[r][0]);
        u[r][1] = fmaf(hv[k], w2v[k].y, u[r][1]);
        u[r][2] = fmaf(hv[k], w2v[k].z, u[r][2]);
        u[r][3] = fmaf(hv[k], w2v[k].w, u[r][3]);
      }
    }
  }
  __syncthreads();  // all ts reads done before aliasing as redb

  // ---- deterministic 8-partial reduce (redb[8][8][256] aliases ts) ----
  float* redb = &ts[0][0];
#pragma unroll
  for (int r = 0; r < 8; ++r) {
    float4 v; v.x = u[r][0]; v.y = u[r][1]; v.z = u[r][2]; v.w = u[r][3];
    *(float4*)&redb[(wv * 8 + r) * 256 + d4] = v;
  }
  __syncthreads();

  // ---- enc = x0 + U + b2f; thread owns one (row, d4) group ----
  {
    const int r = tid >> 6;         // row = wave id
    const int dg = (tid & 63) * 4;  // d-group
    float4 s = *(const float4*)&redb[(0 * 8 + r) * 256 + dg];
#pragma unroll
    for (int w = 1; w < 8; ++w) {
      const float4 p = *(const float4*)&redb[(w * 8 + r) * 256 + dg];
      s.x += p.x; s.y += p.y; s.z += p.z; s.w += p.w;
    }
    const float4 x0 = *(const float4*)&x0s[r][dg];
    const float4 bb = *(const float4*)&b2f[dg];
    float4 e;
    e.x = (x0.x + s.x) + bb.x; e.y = (x0.y + s.y) + bb.y;
    e.z = (x0.z + s.z) + bb.z; e.w = (x0.w + s.w) + bb.w;
    *(float4*)&ws[OFF_ENC + (wg * 8 + r) * Dc + dg] = e;
    *(float4*)&encs[r][dg] = e;
  }
  __syncthreads();

  // ---- z = relu(enc@We1+be1)@We2 + be2 ----
  {
    const int f = tid & 255;  // waves 0-3: rows 0-3; waves 4-7: rows 4-7
    const int rh = tid >> 8;
    float g[4];
    const float be1f = be1[f];
#pragma unroll
    for (int rr = 0; rr < 4; ++rr) g[rr] = be1f;
    for (int c = 0; c < Dc; ++c) {
      const float w = We1[c * Dc + f];
#pragma unroll
      for (int rr = 0; rr < 4; ++rr) g[rr] = fmaf(encs[rh * 4 + rr][c], w, g[rr]);
    }
    const float w2 = We2[f];
#pragma unroll
    for (int rr = 0; rr < 4; ++rr) {
      float p = fmaxf(g[rr], 0.f) * w2;
#pragma unroll
      for (int off = 32; off; off >>= 1) p += __shfl_down(p, off, 64);
      if (lane == 0) zred[wv][rr] = p;
    }
  }
  __syncthreads();
  if (tid < 8) {
    const int r = tid;
    const int wb = (r < 4) ? 0 : 4;
    const int rl = r & 3;
    const float z = ((zred[wb + 0][rl] + zred[wb + 1][rl]) + zred[wb + 2][rl]) +
                    zred[wb + 3][rl];
    ws[OFF_Z + wg * 8 + r] = z + be2[0];
  }
}

// ---- K3: select lstar (fused) + sequential walk via wave shuffles + emit ----
__global__ __launch_bounds__(256) void k_emit(float* __restrict__ ws, float* __restrict__ out) {
  const int b = blockIdx.x;
  const int tid = threadIdx.x;
  __shared__ int lst[Tc];
  __shared__ int path[Tc];
  __shared__ int cnt_s;
  if (tid < Tc) {
    const int i = tid;
    const int lmax = imin(Tc - i, Lc);
    const float* z = ws + OFF_Z + (b * Tc + i) * Lc;
    int ls = lmax;
    for (int l = 1; l <= lmax; ++l) {
      if (z[l - 1] > 0.f) { ls = l; break; }
    }
    lst[tid] = ls;
  }
  __syncthreads();
  if (tid < 64) {  // wave 0: walk via register shuffles (low-latency chain)
    const int a0 = lst[tid], a1 = lst[64 + tid];
    int cur = 0, s = 0;
    while (cur < Tc) {
      const int l = (cur < 64) ? __shfl(a0, cur, 64) : __shfl(a1, cur - 64, 64);
      if (tid == 0) path[s] = cur * Lc + l - 1;
      ++s;
      cur += l;
    }
    if (tid == 0) cnt_s = s;
  }
  __syncthreads();
  const int c = cnt_s;
  for (int s0 = 0; s0 < Tc; s0 += 8) {
    float v[8];
#pragma unroll
    for (int k = 0; k < 8; ++k) {
      const int s = s0 + k;
      v[k] = (s < c) ? ws[OFF_ENC + (b * Tc * Lc + path[s]) * Dc + tid] : 0.f;
    }
#pragma unroll
    for (int k = 0; k < 8; ++k) out[(b * Tc + s0 + k) * Dc + tid] = v[k];
  }
  if (tid == 0) out[Bc * Tc * Dc + b] = (float)c;
}

extern "C" void kernel_launch(void* const* d_in, const int* in_sizes, int n_in,
                              void* d_out, int out_size, void* d_ws, size_t ws_size,
                              hipStream_t stream) {
  const float* frames = (const float*)d_in[0];
  const float* cls    = (const float*)d_in[1];
  const float* Wq     = (const float*)d_in[2];
  const float* bq     = (const float*)d_in[3];
  const float* Wk     = (const float*)d_in[4];
  const float* bk     = (const float*)d_in[5];
  const float* Wv     = (const float*)d_in[6];
  const float* bv     = (const float*)d_in[7];
  const float* Wo     = (const float*)d_in[8];
  const float* bo     = (const float*)d_in[9];
  const float* g1     = (const float*)d_in[10];
  const float* b1     = (const float*)d_in[11];
  const float* g2     = (const float*)d_in[12];
  const float* b2     = (const float*)d_in[13];
  const float* W1     = (const float*)d_in[14];
  const float* b1f    = (const float*)d_in[15];
  const float* W2     = (const float*)d_in[16];
  const float* b2f    = (const float*)d_in[17];
  const float* We1    = (const float*)d_in[18];
  const float* be1    = (const float*)d_in[19];
  const float* We2    = (const float*)d_in[20];
  const float* be2    = (const float*)d_in[21];
  float* ws = (float*)d_ws;
  float* out = (float*)d_out;

  k_prep<<<Bc * Tc + 1, 256, 0, stream>>>(frames, cls, Wq, bq, Wk, bk, Wv, bv, Wo, g1, b1, ws);
  k_fused<<<Bc * Tc, 512, 0, stream>>>(cls, bo, g2, b2, W1, b1f, W2, b2f, We1, be1, We2, be2, ws);
  k_emit<<<Bc, 256, 0, stream>>>(ws, out);
}